// Round 2
// baseline (396.014 us; speedup 1.0000x reference)
//
#include <hip/hip_runtime.h>
#include <hip/hip_bf16.h>

// Problem: B=64, T=4096, D=256, CTX=100
//   logits[b,t] = tanh(X[b,t,:] @ W) @ u ; att = softmax_T(logits)
//   out[b,d]    = sum_t att[b,t] * X[b,t,d]
// Single pass over X (256 MiB): |logits| <= 5 so softmax needs no max-shift;
// accumulate num = sum e^l * x and den = sum e^l in the same kernel.

#define NB 64
#define NT_TOK 4096
#define ND 256
#define NCTX 100
#define NTILE 7            // 7 x 16 = 112 >= 100 ctx columns (zero-padded)
#define KSTEPS 8           // 8 x 32 = 256 = D
#define BLOCKS_PER_B 16
#define NBLOCKS (NB * BLOCKS_PER_B)          // 1024
#define TOK_PER_BLOCK (NT_TOK / BLOCKS_PER_B) // 256
#define TILES_PER_WAVE 4   // 4 waves/block * 4 tiles * 16 tok = 256 tok/block

typedef __attribute__((ext_vector_type(8))) short short8;
typedef __attribute__((ext_vector_type(4))) float f32x4;

// ws layout (bytes):
//   [0, 114688)            : wfrag  — bf16 B-fragments, [NTILE][KSTEPS][64 lanes][8]
//   [114688, 115136)       : upad   — 112 floats (u zero-padded)
//   [115200, 1163776)      : pnum   — per-block partial numerators [1024][256] f32
//   [1163776, 1167872)     : pden   — per-block partial denominators [1024] f32
#define WS_UPAD_OFF 114688
#define WS_PNUM_OFF 115200
#define WS_PDEN_OFF (115200 + 1048576)

__device__ __forceinline__ unsigned short f2bf(float f) {
  unsigned u = __builtin_bit_cast(unsigned, f);
  u += 0x7FFFu + ((u >> 16) & 1u);          // round-to-nearest-even
  return (unsigned short)(u >> 16);
}

__device__ __forceinline__ float tanh_fast(float x) {
  // tanh(x) = 1 - 2/(e^{2x}+1); exact saturation at +/-inf of exp
  float e = __expf(2.0f * x);
  return 1.0f - 2.0f / (e + 1.0f);
}

// Lay out W as bf16 MFMA B-fragments: frag[(nt*KSTEPS+s)*64 + lane][j] =
//   bf16(W[32s + 8*(lane>>4) + j][16nt + (lane&15)])  (0 if col >= 100).
// Same lane->k map is used for the A operand, so the hardware's internal k
// permutation cancels (any bijection works if applied to both A and B).
__global__ void prep_kernel(const float* __restrict__ W, const float* __restrict__ u,
                            unsigned short* __restrict__ wfrag, float* __restrict__ upad) {
  int blk = blockIdx.x;    // nt*KSTEPS + s, 56 blocks
  int l = threadIdx.x;     // 64
  int nt = blk / KSTEPS, s = blk % KSTEPS;
  int col = nt * 16 + (l & 15);
  int kbase = s * 32 + (l >> 4) * 8;
  unsigned short v[8];
#pragma unroll
  for (int j = 0; j < 8; ++j) {
    float f = (col < NCTX) ? W[(size_t)(kbase + j) * NCTX + col] : 0.0f;
    v[j] = f2bf(f);
  }
  unsigned short* dst = wfrag + (size_t)(blk * 64 + l) * 8;
#pragma unroll
  for (int j = 0; j < 8; ++j) dst[j] = v[j];
  if (blk < 2) {
    int c = blk * 64 + l;
    if (c < NTILE * 16) upad[c] = (c < NCTX) ? u[c] : 0.0f;
  }
}

__global__ __launch_bounds__(256, 4) void main_kernel(
    const float* __restrict__ X, const unsigned short* __restrict__ wfrag,
    const float* __restrict__ upad, float* __restrict__ pnum, float* __restrict__ pden) {
  int blk = blockIdx.x;
  int b  = blk / BLOCKS_PER_B;
  int bi = blk % BLOCKS_PER_B;
  int tid = threadIdx.x;
  int wave = tid >> 6;
  int l  = tid & 63;
  int lg = l >> 4;   // k-chunk group 0..3
  int lr = l & 15;   // row (A) / col (B) within tile
  const float* Xb = X + (size_t)b * NT_TOK * ND;
  int tok_base = bi * TOK_PER_BLOCK + wave * (TILES_PER_WAVE * 16);

  float ucol[NTILE];
#pragma unroll
  for (int nt = 0; nt < NTILE; ++nt) ucol[nt] = upad[nt * 16 + lr];

  float accd[4] = {0.f, 0.f, 0.f, 0.f};  // numerator acc for d = 4l..4l+3
  float accden = 0.f;

  __shared__ float snum[4][ND];
  __shared__ float sden[4];

  for (int tile = 0; tile < TILES_PER_WAVE; ++tile) {
    int tok0 = tok_base + tile * 16;
    f32x4 c[NTILE];
#pragma unroll
    for (int nt = 0; nt < NTILE; ++nt) c[nt] = (f32x4){0.f, 0.f, 0.f, 0.f};

    const float* xrow = Xb + (size_t)(tok0 + lr) * ND + lg * 8;
#pragma unroll 2
    for (int s = 0; s < KSTEPS; ++s) {
      f32x4 a0 = *(const f32x4*)(xrow + s * 32);
      f32x4 a1 = *(const f32x4*)(xrow + s * 32 + 4);
      short8 af;
      af[0] = (short)f2bf(a0[0]); af[1] = (short)f2bf(a0[1]);
      af[2] = (short)f2bf(a0[2]); af[3] = (short)f2bf(a0[3]);
      af[4] = (short)f2bf(a1[0]); af[5] = (short)f2bf(a1[1]);
      af[6] = (short)f2bf(a1[2]); af[7] = (short)f2bf(a1[3]);
#pragma unroll
      for (int nt = 0; nt < NTILE; ++nt) {
        short8 bf = *(const short8*)(wfrag + (size_t)((nt * KSTEPS + s) * 64 + l) * 8);
        c[nt] = __builtin_amdgcn_mfma_f32_16x16x32_bf16(af, bf, c[nt], 0, 0, 0);
      }
    }

    // logits: C/D layout (verified m89): reg j, lane l -> row=(l>>4)*4+j, col=l&15
    float sj[4];
#pragma unroll
    for (int j = 0; j < 4; ++j) {
      float t = 0.f;
#pragma unroll
      for (int nt = 0; nt < NTILE; ++nt) t = fmaf(tanh_fast(c[nt][j]), ucol[nt], t);
      sj[j] = t;
    }
    // reduce over 16 columns (lanes sharing lg group)
#pragma unroll
    for (int j = 0; j < 4; ++j) {
      sj[j] += __shfl_xor(sj[j], 1, 64);
      sj[j] += __shfl_xor(sj[j], 2, 64);
      sj[j] += __shfl_xor(sj[j], 4, 64);
      sj[j] += __shfl_xor(sj[j], 8, 64);
    }
    float wj[4];
#pragma unroll
    for (int j = 0; j < 4; ++j) wj[j] = __expf(sj[j]);  // |logit| <= 5, safe

    // weighted accumulation over this tile's 16 rows (cache-hot re-read)
#pragma unroll
    for (int t = 0; t < 16; ++t) {
      float wt = __shfl(wj[t & 3], (t >> 2) * 16, 64);  // lane group t>>2 holds row t
      f32x4 xv = *(const f32x4*)(Xb + (size_t)(tok0 + t) * ND + l * 4);
      accd[0] = fmaf(wt, xv[0], accd[0]);
      accd[1] = fmaf(wt, xv[1], accd[1]);
      accd[2] = fmaf(wt, xv[2], accd[2]);
      accd[3] = fmaf(wt, xv[3], accd[3]);
      accden += wt;
    }
  }

#pragma unroll
  for (int j = 0; j < 4; ++j) snum[wave][l * 4 + j] = accd[j];
  if (l == 0) sden[wave] = accden;
  __syncthreads();
  float s = snum[0][tid] + snum[1][tid] + snum[2][tid] + snum[3][tid];
  pnum[(size_t)blk * ND + tid] = s;
  if (tid == 0) pden[blk] = sden[0] + sden[1] + sden[2] + sden[3];
}

__global__ void fin_kernel(const float* __restrict__ pnum, const float* __restrict__ pden,
                           float* __restrict__ out) {
  int b = blockIdx.x;   // 64
  int d = threadIdx.x;  // 256
  float num = 0.f, den = 0.f;
#pragma unroll
  for (int i = 0; i < BLOCKS_PER_B; ++i) {
    num += pnum[(size_t)(b * BLOCKS_PER_B + i) * ND + d];
    den += pden[b * BLOCKS_PER_B + i];
  }
  out[b * ND + d] = num / den;
}

extern "C" void kernel_launch(void* const* d_in, const int* in_sizes, int n_in,
                              void* d_out, int out_size, void* d_ws, size_t ws_size,
                              hipStream_t stream) {
  const float* X = (const float*)d_in[0];
  const float* W = (const float*)d_in[1];
  const float* u = (const float*)d_in[2];
  float* out = (float*)d_out;
  char* ws = (char*)d_ws;
  unsigned short* wfrag = (unsigned short*)ws;
  float* upad = (float*)(ws + WS_UPAD_OFF);
  float* pnum = (float*)(ws + WS_PNUM_OFF);
  float* pden = (float*)(ws + WS_PDEN_OFF);

  hipLaunchKernelGGL(prep_kernel, dim3(NTILE * KSTEPS), dim3(64), 0, stream, W, u, wfrag, upad);
  hipLaunchKernelGGL(main_kernel, dim3(NBLOCKS), dim3(256), 0, stream, X, wfrag, upad, pnum, pden);
  hipLaunchKernelGGL(fin_kernel, dim3(NB), dim3(ND), 0, stream, pnum, pden, out);
}